// Round 4
// baseline (174.662 us; speedup 1.0000x reference)
//
#include <hip/hip_runtime.h>
#include <hip/hip_bf16.h>
#include <stdint.h>

typedef __bf16 bf16x8 __attribute__((ext_vector_type(8)));
typedef __bf16 bf16x4 __attribute__((ext_vector_type(4)));
typedef float  f32x4  __attribute__((ext_vector_type(4)));
typedef unsigned short u16_t;

#define MFMA(a, b, c) __builtin_amdgcn_mfma_f32_16x16x32_bf16((a), (b), (c), 0, 0, 0)

// async global->LDS, 16B per lane; LDS dest is wave-uniform base + lane*16
__device__ __forceinline__ void cp16(const void* g, void* l) {
  __builtin_amdgcn_global_load_lds(
      (const __attribute__((address_space(1))) unsigned int*)g,
      (__attribute__((address_space(3))) unsigned int*)l, 16, 0, 0);
}

__device__ __forceinline__ unsigned pkbf(float a, float b) {  // pack 2 bf16
  __bf16 x = (__bf16)a, y = (__bf16)b;
  return ((unsigned)*(u16_t*)&y << 16) | (unsigned)*(u16_t*)&x;
}

// ---------------- kernel 1: fused x-convert + W-transpose-convert ----------------
// blocks [0,4096): x fp32 -> bf16.  blocks [4096,4864): W[k][n] fp32 -> Wt[n][k] bf16.
__global__ __launch_bounds__(256) void k_prep(const float* __restrict__ x,
                                              const float* __restrict__ W0,
                                              const float* __restrict__ W1,
                                              const float* __restrict__ W2,
                                              u16_t* __restrict__ xb,
                                              u16_t* __restrict__ Wt) {
  __shared__ u16_t T[64][65];
  int bx = blockIdx.x, t = threadIdx.x;
  if (bx < 4096) {
    int i = bx * 256 + t;
    float4 f = ((const float4*)x)[i];
    bf16x4 o = {(__bf16)f.x, (__bf16)f.y, (__bf16)f.z, (__bf16)f.w};
    *(bf16x4*)&xb[(size_t)i * 4] = o;
    return;
  }
  int j = bx - 4096;
  int nx = j & 15, ny = (j >> 4) & 15, z = j >> 8;
  const float* W = z == 0 ? W0 : (z == 1 ? W1 : W2);
  int k0 = ny * 64, n0 = nx * 64;
#pragma unroll
  for (int i = 0; i < 16; i++) {
    int e = i * 256 + t, r = e >> 6, c = e & 63;
    __bf16 hv = (__bf16)W[(size_t)(k0 + r) * 1024 + n0 + c];
    T[r][c] = *(u16_t*)&hv;
  }
  __syncthreads();
  size_t base = ((size_t)z * 1024 + n0) * 1024 + k0;
#pragma unroll
  for (int i = 0; i < 16; i++) {
    int e = i * 256 + t, r = e >> 6, c = e & 63;
    Wt[base + (size_t)r * 1024 + c] = T[c][r];
  }
}

// ---------------- kernel 2: fused QKV GEMM ----------------
// C[4096,3072] = A[4096,1024] @ Bt[3072,1024]^T, +bias.
// Q: *log2(e)/8 pre-scale, [bh][s][dk]. K: [bh][s][dk]. V: direct-transposed [bh][dk][s].
__global__ __launch_bounds__(256) void k_gemm_qkv(
    const u16_t* __restrict__ A, const u16_t* __restrict__ Bt,
    const float* __restrict__ bq, const float* __restrict__ bk,
    const float* __restrict__ bv,
    u16_t* __restrict__ Qo, u16_t* __restrict__ Ko, u16_t* __restrict__ Vo) {
  __shared__ u16_t As[128 * 32];
  __shared__ u16_t Bs[128 * 32];
  const int tid = threadIdx.x, lane = tid & 63, wv = tid >> 6;
  const int quad = lane >> 4, col = lane & 15;
  const int wm = wv >> 1, wn = wv & 1;
  const int tn = blockIdx.x * 128, tm = blockIdx.y * 128;
  f32x4 acc[4][4] = {};

  const int c0 = wv * 2;
  const int srow = lane >> 2;
  const int spc = lane & 3;

  for (int kk = 0; kk < 1024; kk += 32) {
#pragma unroll
    for (int i = 0; i < 2; i++) {
      int c = c0 + i;
      int m = c * 16 + srow;
      int lch = spc ^ ((m >> 1) & 3);
      cp16(A + (size_t)(tm + m) * 1024 + kk + lch * 8, As + c * 512 + lane * 8);
      cp16(Bt + (size_t)(tn + m) * 1024 + kk + lch * 8, Bs + c * 512 + lane * 8);
    }
    __syncthreads();
    bf16x8 af[4], bfv[4];
#pragma unroll
    for (int mt = 0; mt < 4; mt++) {
      int row = wm * 64 + mt * 16 + col;
      af[mt] = *(const bf16x8*)&As[row * 32 + (quad ^ ((row >> 1) & 3)) * 8];
    }
#pragma unroll
    for (int nt = 0; nt < 4; nt++) {
      int row = wn * 64 + nt * 16 + col;
      bfv[nt] = *(const bf16x8*)&Bs[row * 32 + (quad ^ ((row >> 1) & 3)) * 8];
    }
#pragma unroll
    for (int mt = 0; mt < 4; mt++)
#pragma unroll
      for (int nt = 0; nt < 4; nt++)
        acc[mt][nt] = MFMA(af[mt], bfv[nt], acc[mt][nt]);
    __syncthreads();
  }

  const int mat = tn >> 10;
  const float* bias = mat == 0 ? bq : (mat == 1 ? bk : bv);
  if (mat == 2) {
#pragma unroll
    for (int nt = 0; nt < 4; nt++) {
      int gn = tn + wn * 64 + nt * 16 + col;
      int d = gn & 1023, h = d >> 6, dk = d & 63;
      float bb = bias[d];
#pragma unroll
      for (int mt = 0; mt < 4; mt++) {
        int gm = tm + wm * 64 + mt * 16 + quad * 4;
        int b = gm >> 11, s = gm & 2047;
        bf16x4 pk4;
#pragma unroll
        for (int r = 0; r < 4; r++) pk4[r] = (__bf16)(acc[mt][nt][r] + bb);
        *(bf16x4*)&Vo[((size_t)((b * 16 + h) * 64 + dk)) * 2048 + s] = pk4;
      }
    }
  } else {
    u16_t* O = mat == 0 ? Qo : Ko;
    const float scl = mat == 0 ? 0.18033688011112042f : 1.0f;  // log2(e)/8 in Q
#pragma unroll
    for (int nt = 0; nt < 4; nt++) {
      int gn = tn + wn * 64 + nt * 16 + col;
      int d = gn & 1023, h = d >> 6, dk = d & 63;
      float bb = bias[d];
#pragma unroll
      for (int mt = 0; mt < 4; mt++) {
#pragma unroll
        for (int r = 0; r < 4; r++) {
          int gm = tm + wm * 64 + mt * 16 + quad * 4 + r;
          int b = gm >> 11, s = gm & 2047;
          __bf16 hv = (__bf16)((acc[mt][nt][r] + bb) * scl);
          O[((size_t)((b * 16 + h) * 2048 + s)) * 64 + dk] = *(u16_t*)&hv;
        }
      }
    }
  }
}

// ---------------- kernel 3: fused attention (v4) ----------------
// 256 threads = 4 waves, wave (qh,kh): q-half x key-half of a 64q x 64k tile.
// S^T = K@Q^T; P stored in shared 64-halfword rows per q-half, kh waves
// interleave 8B slots (XOR bits 2-3) -> wave-private dependencies, no mid barrier.
__global__ __launch_bounds__(256, 4) void k_attn(const u16_t* __restrict__ Q,
                                                 const u16_t* __restrict__ K,
                                                 const u16_t* __restrict__ Vt,
                                                 float* __restrict__ out) {
  __shared__ u16_t smem[20480];        // 40 KB
  u16_t* Qs  = smem;                   // 8 KB: Q staging, then P (2 qh x 32q x 64hw)
  u16_t* Ksb = smem + 4096;            // 16 KB dbuf
  u16_t* Vsb = smem + 12288;           // 16 KB dbuf
  const int tid = threadIdx.x, lane = tid & 63, wv = tid >> 6;
  const int quad = lane >> 4, col = lane & 15;
  const int qh = wv >> 1, kh = wv & 1;
  const int qt = blockIdx.x, bh = blockIdx.y;
  const int b = bh >> 4, h = bh & 15;
  const int r8 = lane >> 3, c8 = lane & 7;

  const u16_t* Qg = Q + ((size_t)bh * 2048 + qt * 64) * 64;
  const u16_t* Kg = K + (size_t)bh * 2048 * 64;
  const u16_t* Vg = Vt + (size_t)bh * 64 * 2048;

  // initial staging: Q + K0 + V0 (XOR-8 swizzled 16B chunks, 64-hw rows)
#pragma unroll
  for (int i = 0; i < 2; i++) {
    int c = wv * 2 + i;
    int row = c * 8 + r8;
    int lch = c8 ^ r8;
    cp16(Qg + (size_t)row * 64 + lch * 8, Qs + c * 512 + lane * 8);
    cp16(Kg + (size_t)row * 64 + lch * 8, Ksb + c * 512 + lane * 8);
    cp16(Vg + (size_t)row * 2048 + lch * 8, Vsb + c * 512 + lane * 8);
  }
  __syncthreads();

  // Q fragments (this wave's 32 q) -> registers
  bf16x8 qf[2][2];
#pragma unroll
  for (int nt = 0; nt < 2; nt++)
#pragma unroll
    for (int ks = 0; ks < 2; ks++) {
      int row = qh * 32 + nt * 16 + col;
      qf[nt][ks] = *(const bf16x8*)&Qs[row * 64 + (((ks * 4 + quad) ^ (row & 7)) * 8)];
    }
  __syncthreads();  // Qs region now free for P

  u16_t* Pq = Qs + qh * 2048;  // this q-half's P region: 32q x 64hw
  const int gcol = ((col >> 1) & 3) << 2;  // slot XOR (bits 2-3)

  bf16x8 ones;
#pragma unroll
  for (int j = 0; j < 8; j++) ones[j] = (__bf16)1.0f;

  f32x4 ao[2][4] = {};
  f32x4 dn[2] = {};

  for (int kt = 0; kt < 32; kt++) {
    const int cur = kt & 1;
    const u16_t* Kc = Ksb + cur * 4096;
    const u16_t* Vc = Vsb + cur * 4096;
    if (kt + 1 < 32) {
      u16_t* Kn = Ksb + (cur ^ 1) * 4096;
      u16_t* Vn = Vsb + (cur ^ 1) * 4096;
#pragma unroll
      for (int i = 0; i < 2; i++) {
        int c = wv * 2 + i;
        int row = c * 8 + r8;
        int lch = c8 ^ r8;
        cp16(Kg + (size_t)(kt + 1) * 4096 + (size_t)row * 64 + lch * 8,
             Kn + c * 512 + lane * 8);
        cp16(Vg + (size_t)row * 2048 + (kt + 1) * 64 + lch * 8,
             Vn + c * 512 + lane * 8);
      }
    }

    // S^T = K @ Q^T for this wave's 32k x 32q block
    f32x4 sc[2][2] = {};
#pragma unroll
    for (int ks = 0; ks < 2; ks++) {
      bf16x8 kf[2];
#pragma unroll
      for (int mt = 0; mt < 2; mt++) {
        int row = kh * 32 + mt * 16 + col;
        kf[mt] = *(const bf16x8*)&Kc[row * 64 + (((ks * 4 + quad) ^ (row & 7)) * 8)];
      }
#pragma unroll
      for (int mt = 0; mt < 2; mt++)
#pragma unroll
        for (int nt = 0; nt < 2; nt++)
          sc[mt][nt] = MFMA(kf[mt], qf[nt][ks], sc[mt][nt]);
    }

    // P = exp2(S^T) -> packed b64; slot = (kh*8 + mt*4 + quad) ^ gcol
#pragma unroll
    for (int mt = 0; mt < 2; mt++)
#pragma unroll
      for (int nt = 0; nt < 2; nt++) {
        int q = nt * 16 + col;
        unsigned lo = pkbf(__builtin_amdgcn_exp2f(sc[mt][nt][0]),
                           __builtin_amdgcn_exp2f(sc[mt][nt][1]));
        unsigned hi = pkbf(__builtin_amdgcn_exp2f(sc[mt][nt][2]),
                           __builtin_amdgcn_exp2f(sc[mt][nt][3]));
        int slot = (kh * 8 + mt * 4 + quad) ^ gcol;
        *(uint2*)&Pq[q * 64 + slot * 4] = make_uint2(lo, hi);
      }

    // V fragments (this wave's key half)
    bf16x8 vf[4];
#pragma unroll
    for (int dt = 0; dt < 4; dt++) {
      int row = dt * 16 + col;
      vf[dt] = *(const bf16x8*)&Vc[row * 64 + (((kh * 4 + quad) ^ (row & 7)) * 8)];
    }

    // O += P @ V ; den += P @ 1  (K=32, own-slot readback)
#pragma unroll
    for (int nt = 0; nt < 2; nt++) {
      int q = nt * 16 + col;
      int slot = (kh * 8 + 2 * quad) ^ gcol;
      bf16x8 pf = *(const bf16x8*)&Pq[q * 64 + slot * 4];
      dn[nt] = MFMA(pf, ones, dn[nt]);
#pragma unroll
      for (int dt = 0; dt < 4; dt++)
        ao[nt][dt] = MFMA(pf, vf[dt], ao[nt][dt]);
    }
    __syncthreads();  // staging dbuf rotation
  }

  // cross-wave merge over kh: kh=1 dumps partials, kh=0 adds + normalizes + stores
  float* red = (float*)(smem + 4096);  // 32 KB region (K/V dead)
  const int rb = (qh * 64 + lane) * 41;
  if (kh == 1) {
#pragma unroll
    for (int nt = 0; nt < 2; nt++) {
#pragma unroll
      for (int dt = 0; dt < 4; dt++)
#pragma unroll
        for (int r = 0; r < 4; r++)
          red[rb + (nt * 4 + dt) * 4 + r] = ao[nt][dt][r];
#pragma unroll
      for (int r = 0; r < 4; r++)
        red[rb + 32 + nt * 4 + r] = dn[nt][r];
    }
  }
  __syncthreads();
  if (kh == 0) {
#pragma unroll
    for (int nt = 0; nt < 2; nt++) {
      float dsum[4];
#pragma unroll
      for (int r = 0; r < 4; r++)
        dsum[r] = dn[nt][r] + red[rb + 32 + nt * 4 + r] + 1e-8f;
#pragma unroll
      for (int dt = 0; dt < 4; dt++) {
#pragma unroll
        for (int r = 0; r < 4; r++) {
          float v = (ao[nt][dt][r] + red[rb + (nt * 4 + dt) * 4 + r]) / dsum[r];
          int s = qt * 64 + qh * 32 + nt * 16 + quad * 4 + r;
          out[((size_t)b * 2048 + s) * 1024 + h * 64 + dt * 16 + col] = v;
        }
      }
    }
  }
}

// ---------------- launcher ----------------
extern "C" void kernel_launch(void* const* d_in, const int* in_sizes, int n_in,
                              void* d_out, int out_size, void* d_ws, size_t ws_size,
                              hipStream_t stream) {
  const float* x  = (const float*)d_in[0];
  const float* Wq = (const float*)d_in[1];
  const float* bq = (const float*)d_in[2];
  const float* Wk = (const float*)d_in[3];
  const float* bk = (const float*)d_in[4];
  const float* Wv = (const float*)d_in[5];
  const float* bv = (const float*)d_in[6];
  float* out = (float*)d_out;

  char* ws = (char*)d_ws;
  u16_t* xb  = (u16_t*)(ws);                 // 8 MB   x bf16 [4096][1024]
  u16_t* Wt  = (u16_t*)(ws + 8388608);       // 6 MB   Wt bf16 [3072][1024]
  u16_t* Qb  = (u16_t*)(ws + 14680064);      // 8 MB   Q bf16 [bh][s][dk] (pre-scaled)
  u16_t* Kb  = (u16_t*)(ws + 23068672);      // 8 MB   K bf16 [bh][s][dk]
  u16_t* Vtb = (u16_t*)(ws + 31457280);      // 8 MB   V^T bf16 [bh][dk][s]

  hipLaunchKernelGGL(k_prep, dim3(4864), dim3(256), 0, stream, x, Wq, Wk, Wv, xb, Wt);
  hipLaunchKernelGGL(k_gemm_qkv, dim3(24, 32), dim3(256), 0, stream,
                     xb, Wt, bq, bk, bv, Qb, Kb, Vtb);
  hipLaunchKernelGGL(k_attn, dim3(32, 32), dim3(256), 0, stream, Qb, Kb, Vtb, out);
}

// Round 5
// 170.687 us; speedup vs baseline: 1.0233x; 1.0233x over previous
//
#include <hip/hip_runtime.h>
#include <hip/hip_bf16.h>
#include <stdint.h>

typedef __bf16 bf16x8 __attribute__((ext_vector_type(8)));
typedef __bf16 bf16x4 __attribute__((ext_vector_type(4)));
typedef float  f32x4  __attribute__((ext_vector_type(4)));
typedef short  s16x4  __attribute__((ext_vector_type(4)));
typedef unsigned short u16_t;

#define MFMA(a, b, c)   __builtin_amdgcn_mfma_f32_16x16x32_bf16((a), (b), (c), 0, 0, 0)
#define MFMA16(a, b, c) __builtin_amdgcn_mfma_f32_16x16x16bf16_1k((a), (b), (c), 0, 0, 0)

// async global->LDS, 16B per lane; LDS dest is wave-uniform base + lane*16
__device__ __forceinline__ void cp16(const void* g, void* l) {
  __builtin_amdgcn_global_load_lds(
      (const __attribute__((address_space(1))) unsigned int*)g,
      (__attribute__((address_space(3))) unsigned int*)l, 16, 0, 0);
}

// ---------------- kernel 1: fused x-convert + W-transpose-convert ----------------
__global__ __launch_bounds__(256) void k_prep(const float* __restrict__ x,
                                              const float* __restrict__ W0,
                                              const float* __restrict__ W1,
                                              const float* __restrict__ W2,
                                              u16_t* __restrict__ xb,
                                              u16_t* __restrict__ Wt) {
  __shared__ u16_t T[64][65];
  int bx = blockIdx.x, t = threadIdx.x;
  if (bx < 4096) {
    int i = bx * 256 + t;
    float4 f = ((const float4*)x)[i];
    bf16x4 o = {(__bf16)f.x, (__bf16)f.y, (__bf16)f.z, (__bf16)f.w};
    *(bf16x4*)&xb[(size_t)i * 4] = o;
    return;
  }
  int j = bx - 4096;
  int nx = j & 15, ny = (j >> 4) & 15, z = j >> 8;
  const float* W = z == 0 ? W0 : (z == 1 ? W1 : W2);
  int k0 = ny * 64, n0 = nx * 64;
#pragma unroll
  for (int i = 0; i < 16; i++) {
    int e = i * 256 + t, r = e >> 6, c = e & 63;
    __bf16 hv = (__bf16)W[(size_t)(k0 + r) * 1024 + n0 + c];
    T[r][c] = *(u16_t*)&hv;
  }
  __syncthreads();
  size_t base = ((size_t)z * 1024 + n0) * 1024 + k0;
#pragma unroll
  for (int i = 0; i < 16; i++) {
    int e = i * 256 + t, r = e >> 6, c = e & 63;
    Wt[base + (size_t)r * 1024 + c] = T[c][r];
  }
}

// ---------------- kernel 2: fused QKV GEMM ----------------
__global__ __launch_bounds__(256) void k_gemm_qkv(
    const u16_t* __restrict__ A, const u16_t* __restrict__ Bt,
    const float* __restrict__ bq, const float* __restrict__ bk,
    const float* __restrict__ bv,
    u16_t* __restrict__ Qo, u16_t* __restrict__ Ko, u16_t* __restrict__ Vo) {
  __shared__ u16_t As[128 * 32];
  __shared__ u16_t Bs[128 * 32];
  const int tid = threadIdx.x, lane = tid & 63, wv = tid >> 6;
  const int quad = lane >> 4, col = lane & 15;
  const int wm = wv >> 1, wn = wv & 1;
  const int tn = blockIdx.x * 128, tm = blockIdx.y * 128;
  f32x4 acc[4][4] = {};

  const int c0 = wv * 2;
  const int srow = lane >> 2;
  const int spc = lane & 3;

  for (int kk = 0; kk < 1024; kk += 32) {
#pragma unroll
    for (int i = 0; i < 2; i++) {
      int c = c0 + i;
      int m = c * 16 + srow;
      int lch = spc ^ ((m >> 1) & 3);
      cp16(A + (size_t)(tm + m) * 1024 + kk + lch * 8, As + c * 512 + lane * 8);
      cp16(Bt + (size_t)(tn + m) * 1024 + kk + lch * 8, Bs + c * 512 + lane * 8);
    }
    __syncthreads();
    bf16x8 af[4], bfv[4];
#pragma unroll
    for (int mt = 0; mt < 4; mt++) {
      int row = wm * 64 + mt * 16 + col;
      af[mt] = *(const bf16x8*)&As[row * 32 + (quad ^ ((row >> 1) & 3)) * 8];
    }
#pragma unroll
    for (int nt = 0; nt < 4; nt++) {
      int row = wn * 64 + nt * 16 + col;
      bfv[nt] = *(const bf16x8*)&Bs[row * 32 + (quad ^ ((row >> 1) & 3)) * 8];
    }
#pragma unroll
    for (int mt = 0; mt < 4; mt++)
#pragma unroll
      for (int nt = 0; nt < 4; nt++)
        acc[mt][nt] = MFMA(af[mt], bfv[nt], acc[mt][nt]);
    __syncthreads();
  }

  const int mat = tn >> 10;
  const float* bias = mat == 0 ? bq : (mat == 1 ? bk : bv);
  if (mat == 2) {
#pragma unroll
    for (int nt = 0; nt < 4; nt++) {
      int gn = tn + wn * 64 + nt * 16 + col;
      int d = gn & 1023, h = d >> 6, dk = d & 63;
      float bb = bias[d];
#pragma unroll
      for (int mt = 0; mt < 4; mt++) {
        int gm = tm + wm * 64 + mt * 16 + quad * 4;
        int b = gm >> 11, s = gm & 2047;
        bf16x4 pk4;
#pragma unroll
        for (int r = 0; r < 4; r++) pk4[r] = (__bf16)(acc[mt][nt][r] + bb);
        *(bf16x4*)&Vo[((size_t)((b * 16 + h) * 64 + dk)) * 2048 + s] = pk4;
      }
    }
  } else {
    u16_t* O = mat == 0 ? Qo : Ko;
    const float scl = mat == 0 ? 0.18033688011112042f : 1.0f;  // log2(e)/8 in Q
#pragma unroll
    for (int nt = 0; nt < 4; nt++) {
      int gn = tn + wn * 64 + nt * 16 + col;
      int d = gn & 1023, h = d >> 6, dk = d & 63;
      float bb = bias[d];
#pragma unroll
      for (int mt = 0; mt < 4; mt++) {
#pragma unroll
        for (int r = 0; r < 4; r++) {
          int gm = tm + wm * 64 + mt * 16 + quad * 4 + r;
          int b = gm >> 11, s = gm & 2047;
          __bf16 hv = (__bf16)((acc[mt][nt][r] + bb) * scl);
          O[((size_t)((b * 16 + h) * 2048 + s)) * 64 + dk] = *(u16_t*)&hv;
        }
      }
    }
  }
}

// ---------------- kernel 3: fused attention (v5) ----------------
// 4 waves (qh x kh), wave = 32q x 32k per 64-key stage.
// S^T = K@Q^T via 16x16x32; its C-layout (lane: k=quad*4+r, q=lane&15) IS the
// A-operand layout of mfma_16x16x16_bf16 -> PV consumes exp'd fragments
// directly from registers. NO P LDS round-trip, no cross-lane movement.
__global__ __launch_bounds__(256, 4) void k_attn(const u16_t* __restrict__ Q,
                                                 const u16_t* __restrict__ K,
                                                 const u16_t* __restrict__ Vt,
                                                 float* __restrict__ out) {
  __shared__ u16_t smem[20480];        // 40 KB
  u16_t* Qs  = smem;                   // 8 KB: Q staging (then reduction buffer)
  u16_t* Ksb = smem + 4096;            // 16 KB dbuf: K tiles [64k][64d]
  u16_t* Vsb = smem + 12288;           // 16 KB dbuf: V^T tiles [64d][64k]
  const int tid = threadIdx.x, lane = tid & 63, wv = tid >> 6;
  const int quad = lane >> 4, col = lane & 15;
  const int qh = wv >> 1, kh = wv & 1;
  const int qt = blockIdx.x, bh = blockIdx.y;
  const int b = bh >> 4, h = bh & 15;
  const int r8 = lane >> 3, c8 = lane & 7;

  const u16_t* Qg = Q + ((size_t)bh * 2048 + qt * 64) * 64;
  const u16_t* Kg = K + (size_t)bh * 2048 * 64;
  const u16_t* Vg = Vt + (size_t)bh * 64 * 2048;

  // initial staging: Q + K0 + V0 (row&7 chunk-XOR, measured conflict-free)
#pragma unroll
  for (int i = 0; i < 2; i++) {
    int c = wv * 2 + i;
    int row = c * 8 + r8;
    int lch = c8 ^ r8;
    cp16(Qg + (size_t)row * 64 + lch * 8, Qs + c * 512 + lane * 8);
    cp16(Kg + (size_t)row * 64 + lch * 8, Ksb + c * 512 + lane * 8);
    cp16(Vg + (size_t)row * 2048 + lch * 8, Vsb + c * 512 + lane * 8);
  }
  __syncthreads();

  // Q fragments (this wave's 32 q) -> registers
  bf16x8 qf[2][2];
#pragma unroll
  for (int nt = 0; nt < 2; nt++)
#pragma unroll
    for (int ks = 0; ks < 2; ks++) {
      int row = qh * 32 + nt * 16 + col;
      qf[nt][ks] = *(const bf16x8*)&Qs[row * 64 + (((ks * 4 + quad) ^ (row & 7)) * 8)];
    }

  const short one_bf = (short)0x3F80;  // bf16 1.0
  s16x4 ones4 = {one_bf, one_bf, one_bf, one_bf};

  f32x4 ao[2][4] = {};
  f32x4 dn[2] = {};

  for (int kt = 0; kt < 32; kt++) {
    const int cur = kt & 1;
    const u16_t* Kc = Ksb + cur * 4096;
    const u16_t* Vc = Vsb + cur * 4096;
    if (kt + 1 < 32) {
      u16_t* Kn = Ksb + (cur ^ 1) * 4096;
      u16_t* Vn = Vsb + (cur ^ 1) * 4096;
#pragma unroll
      for (int i = 0; i < 2; i++) {
        int c = wv * 2 + i;
        int row = c * 8 + r8;
        int lch = c8 ^ r8;
        cp16(Kg + (size_t)(kt + 1) * 4096 + (size_t)row * 64 + lch * 8,
             Kn + c * 512 + lane * 8);
        cp16(Vg + (size_t)row * 2048 + (kt + 1) * 64 + lch * 8,
             Vn + c * 512 + lane * 8);
      }
    }

    // S^T = K @ Q^T for this wave's 32k x 32q block (A=K-frag, B=Q-frag)
    f32x4 sc[2][2] = {};
#pragma unroll
    for (int ks = 0; ks < 2; ks++) {
      bf16x8 kf[2];
#pragma unroll
      for (int mt = 0; mt < 2; mt++) {
        int row = kh * 32 + mt * 16 + col;
        kf[mt] = *(const bf16x8*)&Kc[row * 64 + (((ks * 4 + quad) ^ (row & 7)) * 8)];
      }
#pragma unroll
      for (int mt = 0; mt < 2; mt++)
#pragma unroll
        for (int nt = 0; nt < 2; nt++)
          sc[mt][nt] = MFMA(kf[mt], qf[nt][ks], sc[mt][nt]);
    }

    // P = exp2(S^T) in-register -> bf16x4 = A-fragment of 16x16x16 directly
    s16x4 pf[2][2];
#pragma unroll
    for (int mt = 0; mt < 2; mt++)
#pragma unroll
      for (int nt = 0; nt < 2; nt++) {
#pragma unroll
        for (int r = 0; r < 4; r++) {
          __bf16 e = (__bf16)__builtin_amdgcn_exp2f(sc[mt][nt][r]);
          pf[mt][nt][r] = *(short*)&e;
        }
        dn[nt] = MFMA16(pf[mt][nt], ones4, dn[nt]);
      }

    // O += P @ V : B-frag = 4 consecutive keys per lane from V^T tile (b64)
#pragma unroll
    for (int mt = 0; mt < 2; mt++) {
#pragma unroll
      for (int dt = 0; dt < 4; dt++) {
        int row = dt * 16 + col;  // d
        int c = kh * 4 + mt * 2 + (quad >> 1);          // logical 16B chunk (keys)
        int addr = row * 64 + ((c ^ (row & 7)) * 8) + (quad & 1) * 4;
        s16x4 vf = *(const s16x4*)&Vc[addr];
#pragma unroll
        for (int nt = 0; nt < 2; nt++)
          ao[nt][dt] = MFMA16(pf[mt][nt], vf, ao[nt][dt]);
      }
    }
    __syncthreads();  // staging dbuf rotation
  }

  // cross-wave merge over kh: kh=1 dumps partials, kh=0 adds + normalizes + stores
  float* red = (float*)(smem + 4096);  // K/V region dead now
  const int rb = (qh * 64 + lane) * 41;
  if (kh == 1) {
#pragma unroll
    for (int nt = 0; nt < 2; nt++) {
#pragma unroll
      for (int dt = 0; dt < 4; dt++)
#pragma unroll
        for (int r = 0; r < 4; r++)
          red[rb + (nt * 4 + dt) * 4 + r] = ao[nt][dt][r];
#pragma unroll
      for (int r = 0; r < 4; r++)
        red[rb + 32 + nt * 4 + r] = dn[nt][r];
    }
  }
  __syncthreads();
  if (kh == 0) {
#pragma unroll
    for (int nt = 0; nt < 2; nt++) {
      float dsum[4];
#pragma unroll
      for (int r = 0; r < 4; r++)
        dsum[r] = dn[nt][r] + red[rb + 32 + nt * 4 + r] + 1e-8f;
#pragma unroll
      for (int dt = 0; dt < 4; dt++) {
#pragma unroll
        for (int r = 0; r < 4; r++) {
          float v = (ao[nt][dt][r] + red[rb + (nt * 4 + dt) * 4 + r]) / dsum[r];
          int s = qt * 64 + qh * 32 + nt * 16 + quad * 4 + r;
          out[((size_t)b * 2048 + s) * 1024 + h * 64 + dt * 16 + col] = v;
        }
      }
    }
  }
}

// ---------------- launcher ----------------
extern "C" void kernel_launch(void* const* d_in, const int* in_sizes, int n_in,
                              void* d_out, int out_size, void* d_ws, size_t ws_size,
                              hipStream_t stream) {
  const float* x  = (const float*)d_in[0];
  const float* Wq = (const float*)d_in[1];
  const float* bq = (const float*)d_in[2];
  const float* Wk = (const float*)d_in[3];
  const float* bk = (const float*)d_in[4];
  const float* Wv = (const float*)d_in[5];
  const float* bv = (const float*)d_in[6];
  float* out = (float*)d_out;

  char* ws = (char*)d_ws;
  u16_t* xb  = (u16_t*)(ws);                 // 8 MB   x bf16 [4096][1024]
  u16_t* Wt  = (u16_t*)(ws + 8388608);       // 6 MB   Wt bf16 [3072][1024]
  u16_t* Qb  = (u16_t*)(ws + 14680064);      // 8 MB   Q bf16 [bh][s][dk] (pre-scaled)
  u16_t* Kb  = (u16_t*)(ws + 23068672);      // 8 MB   K bf16 [bh][s][dk]
  u16_t* Vtb = (u16_t*)(ws + 31457280);      // 8 MB   V^T bf16 [bh][dk][s]

  hipLaunchKernelGGL(k_prep, dim3(4864), dim3(256), 0, stream, x, Wq, Wk, Wv, xb, Wt);
  hipLaunchKernelGGL(k_gemm_qkv, dim3(24, 32), dim3(256), 0, stream,
                     xb, Wt, bq, bk, bv, Qb, Kb, Vtb);
  hipLaunchKernelGGL(k_attn, dim3(32, 32), dim3(256), 0, stream, Qb, Kb, Vtb, out);
}